// Round 8
// baseline (20.941 us; speedup 1.0000x reference)
//
#include <hip/hip_runtime.h>
#include <math.h>

#define NQ 6
#define DIM 64

typedef _Float16 h8 __attribute__((ext_vector_type(8)));
typedef float f2   __attribute__((ext_vector_type(2)));
typedef float f4   __attribute__((ext_vector_type(4)));
typedef float f64v __attribute__((ext_vector_type(64)));
typedef unsigned int uint;

__device__ __forceinline__ uint pk2(float a, float b) {
    return __builtin_bit_cast(uint, __builtin_amdgcn_cvt_pkrtz(a, b));
}
__device__ __forceinline__ f2 cmul(f2 a, f2 b) {
    return (f2){a.x * b.x - a.y * b.y, a.x * b.y + a.y * b.x};
}

// CNOT-ring permutation: ring-output amp[l] = ring-input amp[R(l)]
struct Perms {
    int R[DIM];
    static constexpr int tau(int l, int c) {
        const int t = (c + 1) % NQ;
        const int cb = 1 << (5 - c), tb = 1 << (5 - t);
        return (l & cb) ? (l ^ tb) : l;
    }
    static constexpr int ring(int l) {
        for (int w = NQ - 1; w >= 0; --w) l = tau(l, w);
        return l;
    }
    constexpr Perms() : R() { for (int l = 0; l < DIM; ++l) R[l] = ring(l); }
};
constexpr Perms PP;

#define MFMA(d, a, b) d = __builtin_amdgcn_mfma_f32_16x16x32_f16((a), (b), (d), 0, 0, 0)

// LDS map (49.5 KB): [0,16K) B1 frag-linear | [16K + 16K*wave, +16K) per-wave A-tile
// (overlaid by epilogue partials) | [48K, +384B) gates g[2][6][8]
__global__ __launch_bounds__(128, 2) void qent_fused(
    const float* __restrict__ x,
    const float* __restrict__ theta, const float* __restrict__ phi,
    const float* __restrict__ omega,
    float* __restrict__ out, int n)
{
    __shared__ __align__(16) char lds[49664];
    const int tid = threadIdx.x;
    const int lane = tid & 63;
    char* b1 = lds;
    char* abase = lds + 16384 + ((tid >> 6) << 14);
    float* g = (float*)(lds + 49152);

    // ---- fused gates V = RX*RY*RZ (12 threads): g[(l*6+w)*8] = {V00r,V00i,V01r,V01i,V10r,V10i,V11r,V11i}
    if (tid < 2 * NQ) {
        int l = tid / NQ, w = tid % NQ;
        float th = theta[l*NQ+w]*0.5f, ph = phi[l*NQ+w]*0.5f, om = omega[l*NQ+w]*0.5f;
        float st_, ct, sp, cp, so, co;
        sincosf(th, &st_, &ct); sincosf(ph, &sp, &cp); sincosf(om, &so, &co);
        float A00r = cp*ct,  A00i = -cp*st_;
        float A01r = -sp*ct, A01i = -sp*st_;
        float A10r = sp*ct,  A10i = -sp*st_;
        float A11r = cp*ct,  A11i = cp*st_;
        float* G = g + (l * NQ + w) * 8;
        G[0] = co*A00r + so*A10i;  G[1] = co*A00i - so*A10r;
        G[2] = co*A01r + so*A11i;  G[3] = co*A01i - so*A11r;
        G[4] = so*A00i + co*A10r;  G[5] = -so*A00r + co*A10i;
        G[6] = so*A01i + co*A11r;  G[7] = -so*A01r + co*A11i;
    }
    __syncthreads();

    // ---- B-build: B[m][col] = K2[R(col)][m] = prod_w V2_w[bit_w(R(col))][bit_w(m)]
    // thread t: col = t&63, h = t>>6 covers m in [h*32, h*32+32). Stacked B1 = [BR ; -BI].
    {
        const int col = tid & 63, h = tid >> 6;
        const int J = PP.R[col];
        const float* g2 = g + NQ * 8;   // layer-2 gates
        f2 T[32];
        {   // wire 0: row bit = bit5 of J, col bit = h
            const float* G = g2 + ((((J >> 5) & 1) * 2 + h) << 1);
            T[0] = (f2){G[0], G[1]};
        }
        #pragma unroll
        for (int w = 1; w < 6; ++w) {
            const int bj = (J >> (5 - w)) & 1;
            const float* Gr = g2 + w * 8 + ((bj * 2) << 1);
            f2 v0 = (f2){Gr[0], Gr[1]};
            f2 v1 = (f2){Gr[2], Gr[3]};
            #pragma unroll
            for (int k = (1 << (w - 1)) - 1; k >= 0; --k) {
                f2 a = T[k];
                T[2*k]   = cmul(a, v0);
                T[2*k+1] = cmul(a, v1);
            }
        }
        const int nt = col >> 4;
        #pragma unroll
        for (int gg = 0; gg < 4; ++gg) {
            uint4 qr, qi;
            qr.x = pk2( T[gg*8+0].x,  T[gg*8+1].x);
            qr.y = pk2( T[gg*8+2].x,  T[gg*8+3].x);
            qr.z = pk2( T[gg*8+4].x,  T[gg*8+5].x);
            qr.w = pk2( T[gg*8+6].x,  T[gg*8+7].x);
            qi.x = pk2(-T[gg*8+0].y, -T[gg*8+1].y);
            qi.y = pk2(-T[gg*8+2].y, -T[gg*8+3].y);
            qi.z = pk2(-T[gg*8+4].y, -T[gg*8+5].y);
            qi.w = pk2(-T[gg*8+6].y, -T[gg*8+7].y);
            // BR rows m=h*32+gg*8+e -> frag (kt=h, nt); -BI rows m+64 -> frag (kt=2+h, nt) = +8192 B
            char* pw = b1 + (h * 4 + nt) * 1024 + ((gg * 16 + (col & 15)) << 4);
            *(uint4*)pw          = qr;
            *(uint4*)(pw + 8192) = qi;
        }
    }

    // ---- encode + layer-1 fold (complex u_w) + complex product expansion ----
    const int gid = blockIdx.x * 128 + tid;
    const int sidx = (gid < n) ? gid : (n - 1);
    const float2* xr = (const float2*)(x + (size_t)sidx * 6);
    float2 x01 = xr[0], x23 = xr[1], x45 = xr[2];
    f2 u0[NQ], u1[NQ];
    #pragma unroll
    for (int w = 0; w < 6; ++w) {
        float xv = (w == 0) ? x01.x : (w == 1) ? x01.y : (w == 2) ? x23.x
                 : (w == 3) ? x23.y : (w == 4) ? x45.x : x45.y;
        xv = fminf(fmaxf(xv, -15.f), 15.f);
        float e2 = __expf(2.f * xv);
        float t = (e2 - 1.f) / (e2 + 1.f);
        float a = t * 1.57079632679489662f;
        float sv, cv;
        __sincosf(a, &sv, &cv);
        const f2* G2 = (const f2*)(g + w * 8);
        f2 cc = {cv, cv}, ss = {sv, sv};
        u0[w] = cc * G2[0] + ss * G2[1];   // V1_w column combo: u0 = V00*c + V01*s
        u1[w] = cc * G2[2] + ss * G2[3];   // u1 = V10*c + V11*s
    }
    f64v ER, EI;
    ER[0] = u0[0].x; EI[0] = u0[0].y;
    ER[1] = u1[0].x; EI[1] = u1[0].y;
    #pragma unroll
    for (int w = 1; w < 6; ++w) {
        #pragma unroll
        for (int k = (1 << w) - 1; k >= 0; --k) {
            float ar = ER[k], ai = EI[k];
            ER[2*k]   = ar * u0[w].x - ai * u0[w].y;
            EI[2*k]   = ar * u0[w].y + ai * u0[w].x;
            ER[2*k+1] = ar * u1[w].x - ai * u1[w].y;
            EI[2*k+1] = ar * u1[w].y + ai * u1[w].x;
        }
    }

    // ---- A-pack: row = lane, stacked K: chunks 0-7 = Re E'[R[.]], 8-15 = Im E'[R[.]] ----
    #pragma unroll
    for (int c = 0; c < 8; ++c) {
        uint4 q, q2;
        q.x  = pk2(ER[PP.R[8*c+0]], ER[PP.R[8*c+1]]);
        q.y  = pk2(ER[PP.R[8*c+2]], ER[PP.R[8*c+3]]);
        q.z  = pk2(ER[PP.R[8*c+4]], ER[PP.R[8*c+5]]);
        q.w  = pk2(ER[PP.R[8*c+6]], ER[PP.R[8*c+7]]);
        q2.x = pk2(EI[PP.R[8*c+0]], EI[PP.R[8*c+1]]);
        q2.y = pk2(EI[PP.R[8*c+2]], EI[PP.R[8*c+3]]);
        q2.z = pk2(EI[PP.R[8*c+4]], EI[PP.R[8*c+5]]);
        q2.w = pk2(EI[PP.R[8*c+6]], EI[PP.R[8*c+7]]);
        *(uint4*)(abase + lane*256 + (( c      ^ (lane & 7)) << 4)) = q;
        *(uint4*)(abase + lane*256 + (((c + 8) ^ (lane & 7)) << 4)) = q2;
    }
    __syncthreads();

    // ---- GEMM: Fr = A·B1 ; Fi(-) = A(kt^2)·B1. M=64 N=64 K=128, 128 MFMA/wave ----
    h8 A[4][4];
    #pragma unroll
    for (int mt = 0; mt < 4; ++mt)
        #pragma unroll
        for (int kt = 0; kt < 4; ++kt)
            A[mt][kt] = *(const h8*)(abase + (mt*16 + (lane & 15))*256 +
                                     (((kt*4 + (lane >> 4)) ^ (lane & 7)) << 4));
    f4 fr[4][4], fi[4][4];
    #pragma unroll
    for (int mt = 0; mt < 4; ++mt)
        #pragma unroll
        for (int nt = 0; nt < 4; ++nt) { fr[mt][nt] = (f4){0,0,0,0}; fi[mt][nt] = (f4){0,0,0,0}; }
    #pragma unroll
    for (int kt = 0; kt < 4; ++kt) {
        h8 B0 = *(const h8*)(b1 + (kt*4 + 0)*1024 + lane*16);
        h8 B1f = *(const h8*)(b1 + (kt*4 + 1)*1024 + lane*16);
        h8 B2 = *(const h8*)(b1 + (kt*4 + 2)*1024 + lane*16);
        h8 B3 = *(const h8*)(b1 + (kt*4 + 3)*1024 + lane*16);
        #pragma unroll
        for (int mt = 0; mt < 4; ++mt) {
            MFMA(fr[mt][0], A[mt][kt], B0);
            MFMA(fr[mt][1], A[mt][kt], B1f);
            MFMA(fr[mt][2], A[mt][kt], B2);
            MFMA(fr[mt][3], A[mt][kt], B3);
            MFMA(fi[mt][0], A[mt][kt^2], B0);
            MFMA(fi[mt][1], A[mt][kt^2], B1f);
            MFMA(fi[mt][2], A[mt][kt^2], B2);
            MFMA(fi[mt][3], A[mt][kt^2], B3);
        }
    }

    // ---- p = Fr^2 + Fi^2 ; epilogue partials (overlay A region, wave-local) ----
    #pragma unroll
    for (int mt = 0; mt < 4; ++mt) {
        #pragma unroll
        for (int r = 0; r < 4; ++r) {
            float q0 = fr[mt][0][r]*fr[mt][0][r] + fi[mt][0][r]*fi[mt][0][r];
            float q1 = fr[mt][1][r]*fr[mt][1][r] + fi[mt][1][r]*fi[mt][1][r];
            float q2 = fr[mt][2][r]*fr[mt][2][r] + fi[mt][2][r]*fi[mt][2][r];
            float q3 = fr[mt][3][r]*fr[mt][3][r] + fi[mt][3][r]*fi[mt][3][r];
            float a_ = q0 + q1, b_ = q2 + q3;
            int s_ = mt*16 + (lane >> 4)*4 + r;
            *(f4*)(abase + s_*256 + (((lane & 15) ^ (s_ & 15)) << 4)) =
                (f4){a_ + b_, a_ - b_, (q0 - q1) + (q2 - q3), 0.f};
        }
    }

    // ---- finish: each lane sums its own sample's 16 col-partials ----
    float z0=0.f, z1=0.f, z2=0.f, z3=0.f, z4=0.f, z5=0.f;
    #pragma unroll
    for (int c = 0; c < 16; ++c) {
        f4 rec = *(const f4*)(abase + lane*256 + ((c ^ (lane & 15)) << 4));
        z0 += rec.y; z1 += rec.z;
        float tot = rec.x;
        z2 += (c & 8) ? -tot : tot;
        z3 += (c & 4) ? -tot : tot;
        z4 += (c & 2) ? -tot : tot;
        z5 += (c & 1) ? -tot : tot;
    }
    if (gid < n) {
        float4* o = (float4*)(out + (size_t)gid * 8);
        o[0] = make_float4(z0, z1, z2, z3);
        o[1] = make_float4(z4, z5, z0, z1);
    }
}

extern "C" void kernel_launch(void* const* d_in, const int* in_sizes, int n_in,
                              void* d_out, int out_size, void* d_ws, size_t ws_size,
                              hipStream_t stream) {
    const float* x     = (const float*)d_in[0];
    const float* theta = (const float*)d_in[1];
    const float* phi   = (const float*)d_in[2];
    const float* omega = (const float*)d_in[3];
    float* out = (float*)d_out;
    int n = in_sizes[0] / NQ;
    int blocks = (n + 127) / 128;
    hipLaunchKernelGGL(qent_fused, dim3(blocks), dim3(128), 0, stream,
                       x, theta, phi, omega, out, n);
}

// Round 9
// 15.585 us; speedup vs baseline: 1.3436x; 1.3436x over previous
//
#include <hip/hip_runtime.h>
#include <math.h>

#define NQ 6

typedef _Float16 h8 __attribute__((ext_vector_type(8)));
typedef float f4   __attribute__((ext_vector_type(4)));
typedef float f8v  __attribute__((ext_vector_type(8)));
typedef float f64v __attribute__((ext_vector_type(64)));
typedef unsigned int uint;

__device__ __forceinline__ uint pk2(float a, float b) {
    return __builtin_bit_cast(uint, __builtin_amdgcn_cvt_pkrtz(a, b));
}

// Fused per-(layer,wire) gate V = RX*RY*RZ
__device__ __forceinline__ void build_gates(const float* theta, const float* phi,
                                            const float* omega, int tid,
                                            float (*g)[NQ][8]) {
    if (tid < 2 * NQ) {
        int l = tid / NQ, w = tid % NQ;
        float th = theta[l*NQ+w]*0.5f, ph = phi[l*NQ+w]*0.5f, om = omega[l*NQ+w]*0.5f;
        float st_, ct, sp, cp, so, co;
        sincosf(th, &st_, &ct); sincosf(ph, &sp, &cp); sincosf(om, &so, &co);
        float A00r = cp*ct,  A00i = -cp*st_;
        float A01r = -sp*ct, A01i = -sp*st_;
        float A10r = sp*ct,  A10i = -sp*st_;
        float A11r = cp*ct,  A11i = cp*st_;
        float* G = g[l][w];
        G[0] = co*A00r + so*A10i;  G[1] = co*A00i - so*A10r;
        G[2] = co*A01r + so*A11i;  G[3] = co*A01i - so*A11r;
        G[4] = so*A00i + co*A10r;  G[5] = -so*A00r + co*A10i;
        G[6] = so*A01i + co*A11r;  G[7] = -so*A01r + co*A11i;
    }
}

// kernel 1: W = full circuit unitary (f16, MFMA B-frag layout). Block j = basis col j.
__global__ __launch_bounds__(64) void qent_prep(
    const float* __restrict__ theta, const float* __restrict__ phi,
    const float* __restrict__ omega, _Float16* __restrict__ W)
{
    __shared__ float g[2][NQ][8];
    const int i = threadIdx.x;
    build_gates(theta, phi, omega, i, g);
    __syncthreads();
    const int j = blockIdx.x;
    float ar = (i == j) ? 1.f : 0.f, ai = 0.f;
    #pragma unroll
    for (int l = 0; l < 2; ++l) {
        #pragma unroll
        for (int w = 0; w < NQ; ++w) {
            const int tb = 1 << (5 - w);
            float pr = __shfl_xor(ar, tb);
            float pi = __shfl_xor(ai, tb);
            const float* G = g[l][w];
            const bool hi = (i & tb) != 0;
            float car = hi ? G[6] : G[0], cai = hi ? G[7] : G[1];
            float cpr = hi ? G[4] : G[2], cpi = hi ? G[5] : G[3];
            float nar = car*ar - cai*ai + cpr*pr - cpi*pi;
            float nai = car*ai + cai*ar + cpr*pi + cpi*pr;
            ar = nar; ai = nai;
        }
        #pragma unroll
        for (int w = 0; w < NQ; ++w) {
            const int cb = 1 << (5 - w), tb = 1 << (5 - ((w + 1) % NQ));
            float pr = __shfl_xor(ar, tb);
            float pi = __shfl_xor(ai, tb);
            if (i & cb) { ar = pr; ai = pi; }
        }
    }
    const int kt = j >> 5, e = j & 7;
    const int nt = i >> 4;
    const int slot = ((j >> 3) & 3) * 16 + (i & 15);
    W[(kt*4 + nt)*512 + slot*8 + e]     = (_Float16)ar;
    W[(8 + kt*4 + nt)*512 + slot*8 + e] = (_Float16)ai;
}

#define MFMA(d, a, b) d = __builtin_amdgcn_mfma_f32_16x16x32_f16((a), (b), (d), 0, 0, 0)
#define LDA(mt, kt) (*(const h8*)(wbase + ((mt)*16 + (lane & 15))*128 + (((((kt)*4) + (lane >> 4)) ^ (lane & 7)) << 4)))

// kernel 2: encode -> E (real), GEMM vs W, |amp|^2, Z-sums.
// All LDS is wave-private (16 KB windows); W lives in registers -> NO block barriers needed.
__global__ __launch_bounds__(256, 2) void qent_main(
    const float* __restrict__ x, const _Float16* __restrict__ Wp,
    float* __restrict__ out, int n)
{
    __shared__ f4 ldsbuf[4096];
    char* lds = (char*)ldsbuf;
    const int tid = threadIdx.x;
    const int lane = tid & 63;
    char* wbase = lds + ((tid >> 6) << 14);
    const int gid = blockIdx.x * 256 + tid;

    const h8* Wv = (const h8*)Wp;
    h8 WR00 = Wv[ 0*64+lane], WR01 = Wv[ 1*64+lane], WR02 = Wv[ 2*64+lane], WR03 = Wv[ 3*64+lane];
    h8 WR10 = Wv[ 4*64+lane], WR11 = Wv[ 5*64+lane], WR12 = Wv[ 6*64+lane], WR13 = Wv[ 7*64+lane];
    h8 WI00 = Wv[ 8*64+lane], WI01 = Wv[ 9*64+lane], WI02 = Wv[10*64+lane], WI03 = Wv[11*64+lane];
    h8 WI10 = Wv[12*64+lane], WI11 = Wv[13*64+lane], WI12 = Wv[14*64+lane], WI13 = Wv[15*64+lane];

    const int sidx = (gid < n) ? gid : (n - 1);
    const float2* xr = (const float2*)(x + (size_t)sidx * 6);
    float2 x01 = xr[0], x23 = xr[1], x45 = xr[2];
    f8v CW, SW;
    #pragma unroll
    for (int w = 0; w < 6; ++w) {
        float xv = (w == 0) ? x01.x : (w == 1) ? x01.y : (w == 2) ? x23.x
                 : (w == 3) ? x23.y : (w == 4) ? x45.x : x45.y;
        xv = fminf(fmaxf(xv, -15.f), 15.f);
        float e2 = __expf(2.f * xv);
        float t = (e2 - 1.f) / (e2 + 1.f);
        float a = t * 1.57079632679489662f;
        float sv, cv;
        __sincosf(a, &sv, &cv);
        CW[w] = cv; SW[w] = sv;
    }

    f64v E;
    E[0] = CW[0]; E[1] = SW[0];
    #pragma unroll
    for (int w = 1; w < 6; ++w) {
        #pragma unroll
        for (int k = (1 << w) - 1; k >= 0; --k) {
            float a = E[k];
            E[2*k]   = a * CW[w];
            E[2*k+1] = a * SW[w];
        }
    }

    #pragma unroll
    for (int k = 0; k < 8; ++k) {
        uint4 q;
        q.x = pk2(E[8*k+0], E[8*k+1]);
        q.y = pk2(E[8*k+2], E[8*k+3]);
        q.z = pk2(E[8*k+4], E[8*k+5]);
        q.w = pk2(E[8*k+6], E[8*k+7]);
        *(uint4*)(wbase + lane*128 + ((k ^ (lane & 7)) << 4)) = q;
    }
    // no __syncthreads: wave-private LDS; per-wave DS ordering suffices

    h8 A00 = LDA(0,0), A10 = LDA(1,0), A20 = LDA(2,0), A30 = LDA(3,0);
    h8 A01 = LDA(0,1), A11 = LDA(1,1), A21 = LDA(2,1), A31 = LDA(3,1);

    f4 c00={0,0,0,0}, c01={0,0,0,0}, c02={0,0,0,0}, c03={0,0,0,0};
    f4 c10={0,0,0,0}, c11={0,0,0,0}, c12={0,0,0,0}, c13={0,0,0,0};
    f4 c20={0,0,0,0}, c21={0,0,0,0}, c22={0,0,0,0}, c23={0,0,0,0};
    f4 c30={0,0,0,0}, c31={0,0,0,0}, c32={0,0,0,0}, c33={0,0,0,0};
    MFMA(c00,A00,WR00); MFMA(c01,A00,WR01); MFMA(c02,A00,WR02); MFMA(c03,A00,WR03);
    MFMA(c10,A10,WR00); MFMA(c11,A10,WR01); MFMA(c12,A10,WR02); MFMA(c13,A10,WR03);
    MFMA(c20,A20,WR00); MFMA(c21,A20,WR01); MFMA(c22,A20,WR02); MFMA(c23,A20,WR03);
    MFMA(c30,A30,WR00); MFMA(c31,A30,WR01); MFMA(c32,A30,WR02); MFMA(c33,A30,WR03);
    MFMA(c00,A01,WR10); MFMA(c01,A01,WR11); MFMA(c02,A01,WR12); MFMA(c03,A01,WR13);
    MFMA(c10,A11,WR10); MFMA(c11,A11,WR11); MFMA(c12,A11,WR12); MFMA(c13,A11,WR13);
    MFMA(c20,A21,WR10); MFMA(c21,A21,WR11); MFMA(c22,A21,WR12); MFMA(c23,A21,WR13);
    MFMA(c30,A31,WR10); MFMA(c31,A31,WR11); MFMA(c32,A31,WR12); MFMA(c33,A31,WR13);
    f4 p00 = c00*c00, p01 = c01*c01, p02 = c02*c02, p03 = c03*c03;
    f4 p10 = c10*c10, p11 = c11*c11, p12 = c12*c12, p13 = c13*c13;
    f4 p20 = c20*c20, p21 = c21*c21, p22 = c22*c22, p23 = c23*c23;
    f4 p30 = c30*c30, p31 = c31*c31, p32 = c32*c32, p33 = c33*c33;
    c00=(f4){0,0,0,0}; c01=(f4){0,0,0,0}; c02=(f4){0,0,0,0}; c03=(f4){0,0,0,0};
    c10=(f4){0,0,0,0}; c11=(f4){0,0,0,0}; c12=(f4){0,0,0,0}; c13=(f4){0,0,0,0};
    c20=(f4){0,0,0,0}; c21=(f4){0,0,0,0}; c22=(f4){0,0,0,0}; c23=(f4){0,0,0,0};
    c30=(f4){0,0,0,0}; c31=(f4){0,0,0,0}; c32=(f4){0,0,0,0}; c33=(f4){0,0,0,0};
    MFMA(c00,A00,WI00); MFMA(c01,A00,WI01); MFMA(c02,A00,WI02); MFMA(c03,A00,WI03);
    MFMA(c10,A10,WI00); MFMA(c11,A10,WI01); MFMA(c12,A10,WI02); MFMA(c13,A10,WI03);
    MFMA(c20,A20,WI00); MFMA(c21,A20,WI01); MFMA(c22,A20,WI02); MFMA(c23,A20,WI03);
    MFMA(c30,A30,WI00); MFMA(c31,A30,WI01); MFMA(c32,A30,WI02); MFMA(c33,A30,WI03);
    MFMA(c00,A01,WI10); MFMA(c01,A01,WI11); MFMA(c02,A01,WI12); MFMA(c03,A01,WI13);
    MFMA(c10,A11,WI10); MFMA(c11,A11,WI11); MFMA(c12,A11,WI12); MFMA(c13,A11,WI13);
    MFMA(c20,A21,WI10); MFMA(c21,A21,WI11); MFMA(c22,A21,WI12); MFMA(c23,A21,WI13);
    MFMA(c30,A31,WI10); MFMA(c31,A31,WI11); MFMA(c32,A31,WI12); MFMA(c33,A31,WI13);
    p00 += c00*c00; p01 += c01*c01; p02 += c02*c02; p03 += c03*c03;
    p10 += c10*c10; p11 += c11*c11; p12 += c12*c12; p13 += c13*c13;
    p20 += c20*c20; p21 += c21*c21; p22 += c22*c22; p23 += c23*c23;
    p30 += c30*c30; p31 += c31*c31; p32 += c32*c32; p33 += c33*c33;
    // no __syncthreads: overlay is wave-private (validated pattern, R8)

#define PART(mt, r) { \
        float q0 = p##mt##0[r], q1 = p##mt##1[r], q2 = p##mt##2[r], q3 = p##mt##3[r]; \
        float a_ = q0 + q1, b_ = q2 + q3; \
        int s_ = (mt)*16 + (lane >> 4)*4 + (r); \
        *(f4*)(wbase + s_*256 + ((((lane & 15)) ^ (s_ & 15)) << 4)) = \
            (f4){a_ + b_, a_ - b_, (q0 - q1) + (q2 - q3), 0.f}; \
    }
    PART(0,0) PART(0,1) PART(0,2) PART(0,3)
    PART(1,0) PART(1,1) PART(1,2) PART(1,3)
    PART(2,0) PART(2,1) PART(2,2) PART(2,3)
    PART(3,0) PART(3,1) PART(3,2) PART(3,3)
#undef PART

    float z0=0.f, z1=0.f, z2=0.f, z3=0.f, z4=0.f, z5=0.f;
    #pragma unroll
    for (int c = 0; c < 16; ++c) {
        f4 rec = *(const f4*)(wbase + lane*256 + ((c ^ (lane & 15)) << 4));
        z0 += rec.y; z1 += rec.z;
        float tot = rec.x;
        z2 += (c & 8) ? -tot : tot;
        z3 += (c & 4) ? -tot : tot;
        z4 += (c & 2) ? -tot : tot;
        z5 += (c & 1) ? -tot : tot;
    }
    if (gid < n) {
        float4* o = (float4*)(out + (size_t)gid * 8);
        o[0] = make_float4(z0, z1, z2, z3);
        o[1] = make_float4(z4, z5, z0, z1);
    }
}

extern "C" void kernel_launch(void* const* d_in, const int* in_sizes, int n_in,
                              void* d_out, int out_size, void* d_ws, size_t ws_size,
                              hipStream_t stream) {
    const float* x     = (const float*)d_in[0];
    const float* theta = (const float*)d_in[1];
    const float* phi   = (const float*)d_in[2];
    const float* omega = (const float*)d_in[3];
    float* out = (float*)d_out;
    _Float16* W = (_Float16*)d_ws;
    int n = in_sizes[0] / NQ;
    hipLaunchKernelGGL(qent_prep, dim3(64), dim3(64), 0, stream, theta, phi, omega, W);
    int blocks = (n + 255) / 256;
    hipLaunchKernelGGL(qent_main, dim3(blocks), dim3(256), 0, stream, x, W, out, n);
}